// Round 3
// baseline (802.844 us; speedup 1.0000x reference)
//
#include <hip/hip_runtime.h>

typedef float v4f __attribute__((ext_vector_type(4)));
typedef short v8s __attribute__((ext_vector_type(8)));
typedef unsigned v4u __attribute__((ext_vector_type(4)));

__device__ __forceinline__ unsigned short f2bf_rn(float f) {
  unsigned u = __float_as_uint(f);
  return (unsigned short)((u + 0x7fffu + ((u >> 16) & 1u)) >> 16);
}

__device__ __forceinline__ float gelu_phi(float x) {
  float t = tanhf(0.7978845608f * (x + 0.044715f * x * x * x));
  return 0.5f * x * (1.0f + t) * 1.5338375f;  // gelu / PHI_C
}

// ---------------- fused MLP + A/W prep (one dispatch, block per b) ----------------
__global__ __launch_bounds__(256) void k_prep(
    const float* __restrict__ emb, const float* __restrict__ x1, const float* __restrict__ x2,
    const float* __restrict__ W0, const float* __restrict__ W1, const float* __restrict__ W2,
    unsigned short* __restrict__ A1, unsigned short* __restrict__ A2, float* __restrict__ W4)
{
  __shared__ float e[64], a1s[256], a2s[256], hsv[64], x1r[256], red[256];
  const int b = blockIdx.x, tid = threadIdx.x;
  if (tid < 64) e[tid] = emb[b * 64 + tid];
  x1r[tid] = x1[b * 256 + tid];
  {  // W4[v][b][{s2, v2_0..2}]
    const int v = tid >> 2, c = tid & 3;
    const float val = (c == 0) ? x2[b * 256 + v] : x2[b * 256 + 64 + v * 3 + (c - 1)];
    W4[(v * 128 + b) * 4 + c] = val;
  }
  __syncthreads();
  float s1a = 0.f;
#pragma unroll 8
  for (int x = 0; x < 64; ++x) s1a += e[x] * W0[x * 256 + tid];
  a1s[tid] = gelu_phi(s1a * 0.125f);
  __syncthreads();
  float s2a = 0.f;
#pragma unroll 16
  for (int x = 0; x < 256; ++x) s2a += a1s[x] * W1[x * 256 + tid];
  a2s[tid] = gelu_phi(s2a * 0.0625f);
  __syncthreads();
  const int ee = tid & 63, xq = tid >> 6;
  float s3a = 0.f;
#pragma unroll 8
  for (int xx = 0; xx < 64; ++xx) s3a += a2s[xq * 64 + xx] * W2[(xq * 64 + xx) * 64 + ee];
  red[tid] = s3a;
  __syncthreads();
  if (tid < 64)
    hsv[tid] = gelu_phi((red[tid] + red[64 + tid] + red[128 + tid] + red[192 + tid]) * 0.0625f) * 0.125f;
  __syncthreads();
  // A1[b][x*64+u] = bf16(hs_s * s1[b,u]);  A2[g*128+b][x*64+u] = bf16(hs_s * v1[b,u,g])
  const float hv = hsv[tid >> 2];
  const int u0 = (tid & 3) * 16;
  const size_t rowoff = (size_t)(tid >> 2) * 64 + u0;
  unsigned short tmp[16];
#pragma unroll
  for (int i = 0; i < 16; ++i) tmp[i] = f2bf_rn(hv * x1r[u0 + i]);
  {
    v8s* o = (v8s*)(A1 + (size_t)b * 4096 + rowoff);
    o[0] = *(v8s*)&tmp[0];
    o[1] = *(v8s*)&tmp[8];
  }
#pragma unroll
  for (int g = 0; g < 3; ++g) {
#pragma unroll
    for (int i = 0; i < 16; ++i) tmp[i] = f2bf_rn(hv * x1r[64 + (u0 + i) * 3 + g]);
    v8s* o = (v8s*)(A2 + (size_t)(g * 128 + b) * 4096 + rowoff);
    o[0] = *(v8s*)&tmp[0];
    o[1] = *(v8s*)&tmp[8];
  }
}

// ---------------- main GEMM with in-register v-contraction ----------------
// Slabs (M=128 each): s=0: A1 x P0 -> plane 0 (s2 wgt, A01)      [t0]
//                     s=1: A1 x P1 -> planes 1..3 (v2j, A01)     [t1]
//                 s=2..4: A2_i x P2 -> plane 4+i (s2, A01)       [t2]
//                 s=5..7: A2_i x P3 -> plane 7+i (v2i, A01IS3)   [t3]
//                s=8..10: A2_i x P4 -> planes 10+2i (-v2[(i+2)%3], A2C), 11+2i (+v2[(i+1)%3], A2C) [t4]
// Block = (slab, wchunk 0..3, ks 0..31). K-chunk=128. LDS tile = 32k x (4v x 16w), zero-conflict layout.
// Heavy i-triples share a P slab read; swizzled to co-schedule (bid pattern g*24 + i*8 + x).
__global__ __launch_bounds__(256, 3) void gemm_k(
    const float* __restrict__ P0, const float* __restrict__ P1, const float* __restrict__ P2,
    const float* __restrict__ P3, const float* __restrict__ P4,
    const unsigned short* __restrict__ A1, const unsigned short* __restrict__ A2,
    const float* __restrict__ W4, float* __restrict__ PB)
{
  __shared__ unsigned ldsB[16 * 68];
  __shared__ float ldsW[2048];
  const int tid = threadIdx.x;
  const int bid = blockIdx.x;
  int s, wc, ks;
  if (bid < 1152) {  // heavy: slabs 2..10
    const int g = bid / 24, r = bid - g * 24;
    const int x = r & 7, i = r >> 3;
    const int T = g * 8 + x;      // triple id 0..383
    const int ps = T >> 7;        // P2/P3/P4
    const int rem = T & 127;
    wc = rem >> 5;
    ks = rem & 31;
    s = 2 + ps * 3 + i;
  } else {  // light: slabs 0,1
    const int u = bid - 1152;
    s = u >> 7;
    const int rem = u & 127;
    wc = rem >> 5;
    ks = rem & 31;
  }
  const int i3 = (s >= 2) ? ((s - 2) % 3) : 0;
  const float* __restrict__ P =
      (s == 0) ? P0 : (s == 1) ? P1 : (s < 5) ? P2 : (s < 8) ? P3 : P4;
  const unsigned short* __restrict__ A = (s < 2) ? A1 : (A2 + (size_t)i3 * 128 * 4096);

  const int lane = tid & 63, wav = tid >> 6;
  const int l16 = lane & 15, quad = lane >> 4;
  const int tq = tid & 15, kp = tid >> 4;

  // preload A fragments: af[t][kk], row = 16*(wav+4t)+l16, k = ks*128 + kk*32 + quad*8
  v8s af[2][4];
#pragma unroll
  for (int t = 0; t < 2; ++t)
#pragma unroll
    for (int kk = 0; kk < 4; ++kk)
      af[t][kk] = *(const v8s*)(A + (size_t)(16 * (wav + 4 * t) + l16) * 4096 + ks * 128 + kk * 32 + quad * 8);

  // staging base: rows k = ks*128 + kk*32 + 2kp(+1); cols = (vg*4 + tq>>2)*64 + wc*16 + 4*(tq&3)
  const float* Pbase = P + (size_t)(ks * 128 + 2 * kp) * 4096 + (size_t)(tq >> 2) * 64 + wc * 16 + 4 * (tq & 3);

  float4 pr0, pr1;
  {
    const float* p = Pbase;
    pr0 = *(const float4*)p;
    pr1 = *(const float4*)(p + 4096);
  }

  v4f o[3][2];
#pragma unroll
  for (int a = 0; a < 3; ++a)
#pragma unroll
    for (int t = 0; t < 2; ++t) o[a][t] = (v4f){0.f, 0.f, 0.f, 0.f};

  for (int vg = 0; vg < 16; ++vg) {
    // early-issue weight loads for this vgroup (consumed after k-loop)
    const float4 w0r = *(const float4*)(W4 + vg * 2048 + tid * 8);
    const float4 w1r = *(const float4*)(W4 + vg * 2048 + tid * 8 + 4);
    v4f acc[2][4];
#pragma unroll
    for (int t = 0; t < 2; ++t)
#pragma unroll
      for (int nf = 0; nf < 4; ++nf) acc[t][nf] = (v4f){0.f, 0.f, 0.f, 0.f};

#pragma unroll
    for (int kk = 0; kk < 4; ++kk) {
      __syncthreads();
      {
        v4u d;
        d.x = (unsigned)f2bf_rn(pr0.x) | ((unsigned)f2bf_rn(pr1.x) << 16);
        d.y = (unsigned)f2bf_rn(pr0.y) | ((unsigned)f2bf_rn(pr1.y) << 16);
        d.z = (unsigned)f2bf_rn(pr0.z) | ((unsigned)f2bf_rn(pr1.z) << 16);
        d.w = (unsigned)f2bf_rn(pr0.w) | ((unsigned)f2bf_rn(pr1.w) << 16);
        *(v4u*)&ldsB[kp * 68 + 4 * tq] = d;
      }
      __syncthreads();
      {  // prefetch next tile (clamped on last)
        int nvg = vg, nkk = kk + 1;
        if (nkk == 4) { nkk = 0; ++nvg; if (nvg == 16) { nvg = 15; nkk = 3; } }
        const float* p = Pbase + nvg * 256 + (size_t)nkk * 131072;
        pr0 = *(const float4*)p;
        pr1 = *(const float4*)(p + 4096);
      }
      union { unsigned u[4]; v8s s8; } bf[4];
#pragma unroll
      for (int nf = 0; nf < 4; ++nf)
#pragma unroll
        for (int jj = 0; jj < 4; ++jj)
          bf[nf].u[jj] = ldsB[(quad * 4 + jj) * 68 + nf * 16 + l16];
#pragma unroll
      for (int t = 0; t < 2; ++t)
#pragma unroll
        for (int nf = 0; nf < 4; ++nf)
          acc[t][nf] = __builtin_amdgcn_mfma_f32_16x16x32_bf16(af[t][kk], bf[nf].s8, acc[t][nf], 0, 0, 0);
    }

    // stage weights (previous epilogue readers passed kk-loop barriers)
    *(float4*)&ldsW[tid * 8] = w0r;
    *(float4*)&ldsW[tid * 8 + 4] = w1r;
    __syncthreads();

    // contract this vgroup's 4 v into out-accs; ldsW[nf*512 + b*4 + c], broadcast across l16
#pragma unroll
    for (int t = 0; t < 2; ++t)
#pragma unroll
      for (int r = 0; r < 4; ++r) {
        const int bb = 16 * (wav + 4 * t) + quad * 4 + r;
#pragma unroll
        for (int nf = 0; nf < 4; ++nf) {
          const float g = acc[t][nf][r];
          const int base = nf * 512 + bb * 4;
          if (s == 0 || (s >= 2 && s < 5)) {
            o[0][t][r] += ldsW[base] * g;
          } else if (s == 1) {
            o[0][t][r] += ldsW[base + 1] * g;
            o[1][t][r] += ldsW[base + 2] * g;
            o[2][t][r] += ldsW[base + 3] * g;
          } else if (s < 8) {
            o[0][t][r] += ldsW[base + 1 + i3] * g;
          } else {
            o[0][t][r] += ldsW[base + 1 + (i3 + 2) % 3] * g;  // -> plane 10+2i, negated
            o[1][t][r] += ldsW[base + 1 + (i3 + 1) % 3] * g;  // -> plane 11+2i
          }
        }
      }
  }

  // ---- write weighted partials: PB[ks][plane][b][w] ----
  const float A01 = 0.011048543f;      // 1/sqrt(2*64*64)
  const float A01IS3 = 0.0063793777f;  // A01/sqrt(3)
  const float A2C = 0.011048543f;      // (1/64)*(1/sqrt(2))
  int pl[3] = {0, 0, 0}, npl;
  float sc[3] = {0.f, 0.f, 0.f};
  if (s == 0) { npl = 1; pl[0] = 0; sc[0] = A01; }
  else if (s == 1) { npl = 3; pl[0] = 1; pl[1] = 2; pl[2] = 3; sc[0] = sc[1] = sc[2] = A01; }
  else if (s < 5) { npl = 1; pl[0] = 4 + i3; sc[0] = A01; }
  else if (s < 8) { npl = 1; pl[0] = 7 + i3; sc[0] = A01IS3; }
  else { npl = 2; pl[0] = 10 + 2 * i3; sc[0] = -A2C; pl[1] = 11 + 2 * i3; sc[1] = A2C; }
  for (int a = 0; a < npl; ++a)
#pragma unroll
    for (int t = 0; t < 2; ++t)
#pragma unroll
      for (int r = 0; r < 4; ++r) {
        const int bb = 16 * (wav + 4 * t) + quad * 4 + r;
        PB[(size_t)ks * 131072 + pl[a] * 8192 + bb * 64 + wc * 16 + l16] = sc[a] * o[a][t][r];
      }
}

// ---------------- sum over ks slots ----------------
__global__ __launch_bounds__(256) void k_sum1(const float* __restrict__ PB, float* __restrict__ PB2)
{
  const int idx = blockIdx.x * 256 + threadIdx.x;  // 131072
  float s = 0.f;
#pragma unroll 8
  for (int ks = 0; ks < 32; ++ks) s += PB[(size_t)ks * 131072 + idx];
  PB2[idx] = s;
}

// ---------------- assemble output ----------------
__global__ __launch_bounds__(256) void k_finish(const float* __restrict__ PB2, float* __restrict__ out)
{
  const int o = blockIdx.x * 256 + threadIdx.x;  // 57344
  const int b = o / 448, r = o - b * 448;
  float s;
  if (r < 64) {
    const int w = r;
    s = PB2[0 * 8192 + b * 64 + w] + PB2[7 * 8192 + b * 64 + w] +
        PB2[8 * 8192 + b * 64 + w] + PB2[9 * 8192 + b * 64 + w];
  } else if (r < 256) {
    const int q = r - 64, w = q / 3, c = q - w * 3;
    s = PB2[(1 + c) * 8192 + b * 64 + w] + PB2[(4 + c) * 8192 + b * 64 + w];
  } else {
    const int q = r - 256, w = q / 3, k = q - w * 3;
    s = PB2[(10 + 2 * ((k + 2) % 3)) * 8192 + b * 64 + w] +
        PB2[(11 + 2 * ((k + 1) % 3)) * 8192 + b * 64 + w];
  }
  out[o] = s;
}

extern "C" void kernel_launch(void* const* d_in, const int* in_sizes, int n_in,
                              void* d_out, int out_size, void* d_ws, size_t ws_size,
                              hipStream_t stream)
{
  const float* emb = (const float*)d_in[0];
  const float* x1  = (const float*)d_in[1];
  const float* x2  = (const float*)d_in[2];
  const float* W0  = (const float*)d_in[3];
  const float* W1  = (const float*)d_in[4];
  const float* W2  = (const float*)d_in[5];
  const float* P0  = (const float*)d_in[6];
  const float* P1  = (const float*)d_in[7];
  const float* P2  = (const float*)d_in[8];
  const float* P3  = (const float*)d_in[9];
  const float* P4  = (const float*)d_in[10];
  float* out = (float*)d_out;
  char* ws = (char*)d_ws;

  unsigned short* A1 = (unsigned short*)ws;                 // 1 MB
  unsigned short* A2 = (unsigned short*)(ws + 1048576);     // 3 MB
  float* W4 = (float*)(ws + 4194304);                       // 128 KB
  float* PB = (float*)(ws + 4718592);                       // 32*16*8192*4 = 16 MB
  float* PB2 = (float*)(ws + 4718592 + 16777216);           // 512 KB

  k_prep<<<128, 256, 0, stream>>>(emb, x1, x2, W0, W1, W2, A1, A2, W4);
  gemm_k<<<1408, 256, 0, stream>>>(P0, P1, P2, P3, P4, A1, A2, W4, PB);
  k_sum1<<<512, 256, 0, stream>>>(PB, PB2);
  k_finish<<<224, 256, 0, stream>>>(PB2, out);
}